// Round 1
// baseline (285.865 us; speedup 1.0000x reference)
//
#include <hip/hip_runtime.h>
#include <hip/hip_bf16.h>

typedef __bf16 bf16;
typedef __bf16 bf16x8 __attribute__((ext_vector_type(8)));
typedef float f32x4 __attribute__((ext_vector_type(4)));

#define EMB 768
#define NH 12
#define HD 64
#define SEQ 2048
#define NBATCH 2
#define NREL (2 * SEQ - 1)

// XOR-swizzle for 128B-row-stride LDS tiles: moves row&7 (bits 7-9) into the
// 16B-slot index (bits 4-6). Bijective per row; write and read both apply it.
__device__ __forceinline__ int swz(int bo) { return bo ^ ((bo >> 3) & 0x70); }

// ---------------- bias bucket table: bias_tab[h][rel + 2047] ----------------
__global__ void k_bias_table(const float* __restrict__ rel_bias,
                             float* __restrict__ bias_tab) {
  int i = blockIdx.x * 256 + threadIdx.x;
  if (i >= NREL) return;
  int rel = i - (SEQ - 1);            // rel = s - t
  int bkt = (rel > 0) ? 16 : 0;
  int rp = rel < 0 ? -rel : rel;
  if (rp < 8) {
    bkt += rp;
  } else {
    // mirror: log(rp/8) / log(16) * 8, f32, trunc toward zero
    float lf = (logf((float)rp * 0.125f) / 2.7725887222397811f) * 8.0f;
    int large = 8 + (int)lf;
    bkt += (large < 15) ? large : 15;
  }
  for (int h = 0; h < NH; ++h)
    bias_tab[h * NREL + i] = rel_bias[bkt * NH + h];
}

// ------------- QKV projection: f32 X[4096][768] @ f32 W[768][768] -----------
// out bf16 [B][H][T][D], value = (acc + bias) * scale
__global__ __launch_bounds__(256) void k_proj_qkv(
    const float* __restrict__ A, const float* __restrict__ W,
    const float* __restrict__ bias, bf16* __restrict__ outh, float scale) {
  __shared__ __align__(16) bf16 As[64 * 32];   // [m][k]
  __shared__ __align__(16) bf16 Bs[64 * 32];   // [n][k]
  const int m0 = blockIdx.x * 64, n0 = blockIdx.y * 64;
  const int tid = threadIdx.x;
  const int lane = tid & 63, w = tid >> 6;
  const int c = lane & 15, g = lane >> 4;
  const int mo = (w >> 1) * 32, no = (w & 1) * 32;
  f32x4 acc[2][2] = {};
  for (int k0 = 0; k0 < EMB; k0 += 32) {
    __syncthreads();
    {
      const int row = tid >> 2, kc = (tid & 3) * 8;
      const float* ap = A + (size_t)(m0 + row) * EMB + k0 + kc;
      float4 f0 = *(const float4*)ap;
      float4 f1 = *(const float4*)(ap + 4);
      bf16x8 v;
      v[0] = (bf16)f0.x; v[1] = (bf16)f0.y; v[2] = (bf16)f0.z; v[3] = (bf16)f0.w;
      v[4] = (bf16)f1.x; v[5] = (bf16)f1.y; v[6] = (bf16)f1.z; v[7] = (bf16)f1.w;
      *(bf16x8*)&As[row * 32 + kc] = v;
      const int kr = tid >> 3, nc = (tid & 7) * 8;
      const float* wp = W + (size_t)(k0 + kr) * EMB + n0 + nc;
      float4 w0 = *(const float4*)wp;
      float4 w1 = *(const float4*)(wp + 4);
      float wv[8] = {w0.x, w0.y, w0.z, w0.w, w1.x, w1.y, w1.z, w1.w};
#pragma unroll
      for (int j = 0; j < 8; ++j) Bs[(nc + j) * 32 + kr] = (bf16)wv[j];
    }
    __syncthreads();
#pragma unroll
    for (int mf = 0; mf < 2; ++mf) {
      bf16x8 a = *(const bf16x8*)&As[(mo + mf * 16 + c) * 32 + g * 8];
#pragma unroll
      for (int nf = 0; nf < 2; ++nf) {
        bf16x8 bfr = *(const bf16x8*)&Bs[(no + nf * 16 + c) * 32 + g * 8];
        acc[mf][nf] = __builtin_amdgcn_mfma_f32_16x16x32_bf16(a, bfr, acc[mf][nf], 0, 0, 0);
      }
    }
  }
#pragma unroll
  for (int mf = 0; mf < 2; ++mf)
#pragma unroll
    for (int nf = 0; nf < 2; ++nf)
#pragma unroll
      for (int r = 0; r < 4; ++r) {
        int m = m0 + mo + mf * 16 + g * 4 + r;
        int n = n0 + no + nf * 16 + c;
        float v = (acc[mf][nf][r] + bias[n]) * scale;
        int t = m >> 1, b = m & 1;       // row = t*B + b
        int h = n >> 6, d = n & 63;
        outh[((size_t)(b * NH + h) * SEQ + t) * HD + d] = (bf16)v;
      }
}

// ------------- output projection: bf16 A[4096][768] @ Wo + bo -> f32 --------
__global__ __launch_bounds__(256) void k_proj_out(
    const bf16* __restrict__ A, const float* __restrict__ W,
    const float* __restrict__ bias, float* __restrict__ out) {
  __shared__ __align__(16) bf16 As[64 * 32];
  __shared__ __align__(16) bf16 Bs[64 * 32];
  const int m0 = blockIdx.x * 64, n0 = blockIdx.y * 64;
  const int tid = threadIdx.x;
  const int lane = tid & 63, w = tid >> 6;
  const int c = lane & 15, g = lane >> 4;
  const int mo = (w >> 1) * 32, no = (w & 1) * 32;
  f32x4 acc[2][2] = {};
  for (int k0 = 0; k0 < EMB; k0 += 32) {
    __syncthreads();
    {
      const int row = tid >> 2, kc = (tid & 3) * 8;
      *(bf16x8*)&As[row * 32 + kc] =
          *(const bf16x8*)(A + (size_t)(m0 + row) * EMB + k0 + kc);
      const int kr = tid >> 3, nc = (tid & 7) * 8;
      const float* wp = W + (size_t)(k0 + kr) * EMB + n0 + nc;
      float4 w0 = *(const float4*)wp;
      float4 w1 = *(const float4*)(wp + 4);
      float wv[8] = {w0.x, w0.y, w0.z, w0.w, w1.x, w1.y, w1.z, w1.w};
#pragma unroll
      for (int j = 0; j < 8; ++j) Bs[(nc + j) * 32 + kr] = (bf16)wv[j];
    }
    __syncthreads();
#pragma unroll
    for (int mf = 0; mf < 2; ++mf) {
      bf16x8 a = *(const bf16x8*)&As[(mo + mf * 16 + c) * 32 + g * 8];
#pragma unroll
      for (int nf = 0; nf < 2; ++nf) {
        bf16x8 bfr = *(const bf16x8*)&Bs[(no + nf * 16 + c) * 32 + g * 8];
        acc[mf][nf] = __builtin_amdgcn_mfma_f32_16x16x32_bf16(a, bfr, acc[mf][nf], 0, 0, 0);
      }
    }
  }
#pragma unroll
  for (int mf = 0; mf < 2; ++mf)
#pragma unroll
    for (int nf = 0; nf < 2; ++nf)
#pragma unroll
      for (int r = 0; r < 4; ++r) {
        int m = m0 + mo + mf * 16 + g * 4 + r;
        int n = n0 + no + nf * 16 + c;
        out[(size_t)m * EMB + n] = acc[mf][nf][r] + bias[n];
      }
}

// ----------------------------- flash attention ------------------------------
// grid (B*H, T/64); per block: Q-tile 64 rows, loop over 32 S-tiles of 64.
__global__ __launch_bounds__(256) void k_attn(
    const bf16* __restrict__ qh, const bf16* __restrict__ kh,
    const bf16* __restrict__ vh, const unsigned char* __restrict__ mask,
    const float* __restrict__ bias_tab, bf16* __restrict__ attn_out) {
  __shared__ __align__(16) bf16 Qs[64 * 64];   // [t][d]  swizzled
  __shared__ __align__(16) bf16 Ks[64 * 64];   // [s][d]  swizzled
  __shared__ __align__(16) bf16 Vt[64 * 64];   // [d][s]  swizzled
  __shared__ __align__(16) bf16 Ps[64 * 64];   // [t][s]  swizzled
  __shared__ float bloc[127];
  __shared__ unsigned char mloc[64];
  const int bh = blockIdx.x;
  const int b = bh / NH, h = bh % NH;
  const int t0 = blockIdx.y * 64;
  const int tid = threadIdx.x;
  const int lane = tid & 63, w = tid >> 6;
  const int c = lane & 15, g = lane >> 4;
  const float NEGINF = -__builtin_inff();

  {  // stage Q once (rows are contiguous: 8KB block)
    const uint4* qg = (const uint4*)(qh + ((size_t)bh * SEQ + t0) * HD);
    for (int i = tid; i < 512; i += 256)
      *(uint4*)((char*)Qs + swz(i * 16)) = qg[i];
  }
  float mrow[4] = {-1e30f, -1e30f, -1e30f, -1e30f};
  float lrow[4] = {0.f, 0.f, 0.f, 0.f};
  f32x4 o[4] = {};
  const float* btab = bias_tab + h * NREL + (SEQ - 1);
  const int trl = w * 16 + g * 4;  // block-local t of acc row r=0

  for (int s0 = 0; s0 < SEQ; s0 += 64) {
    __syncthreads();
    const uint4* kg = (const uint4*)(kh + ((size_t)bh * SEQ + s0) * HD);
    for (int i = tid; i < 512; i += 256)
      *(uint4*)((char*)Ks + swz(i * 16)) = kg[i];
    const uint4* vg = (const uint4*)(vh + ((size_t)bh * SEQ + s0) * HD);
    for (int i = tid; i < 512; i += 256) {  // transpose V on store
      int s = i >> 3, d0 = (i & 7) * 8;
      union { uint4 u; bf16 e[8]; } tv;
      tv.u = vg[i];
#pragma unroll
      for (int j = 0; j < 8; ++j)
        *(bf16*)((char*)Vt + swz(((d0 + j) * 64 + s) * 2)) = tv.e[j];
    }
    if (tid < 127) bloc[tid] = btab[(s0 - t0) + tid - 63];
    if (tid < 64) mloc[tid] = mask[b * SEQ + s0 + tid];
    __syncthreads();

    // QK^T: wave w owns t-rows [16w,16w+16), all 64 s-cols
    f32x4 sacc[4] = {};
#pragma unroll
    for (int kk = 0; kk < 2; ++kk) {
      bf16x8 a = *(const bf16x8*)((char*)Qs + swz((w * 16 + c) * 128 + (kk * 32 + g * 8) * 2));
#pragma unroll
      for (int nf = 0; nf < 4; ++nf) {
        bf16x8 kb = *(const bf16x8*)((char*)Ks + swz((nf * 16 + c) * 128 + (kk * 32 + g * 8) * 2));
        sacc[nf] = __builtin_amdgcn_mfma_f32_16x16x32_bf16(a, kb, sacc[nf], 0, 0, 0);
      }
    }
    // bias + mask + tile row-max
    float tmax[4] = {NEGINF, NEGINF, NEGINF, NEGINF};
#pragma unroll
    for (int nf = 0; nf < 4; ++nf) {
      int sl = c + nf * 16;
      bool mk = mloc[sl] != 0;
#pragma unroll
      for (int r = 0; r < 4; ++r) {
        float v = sacc[nf][r] + bloc[sl - (trl + r) + 63];
        if (mk) v = NEGINF;
        sacc[nf][r] = v;
        tmax[r] = fmaxf(tmax[r], v);
      }
    }
#pragma unroll
    for (int mm = 1; mm < 16; mm <<= 1)
#pragma unroll
      for (int r = 0; r < 4; ++r)
        tmax[r] = fmaxf(tmax[r], __shfl_xor(tmax[r], mm, 64));
    // online-softmax update
    float scl[4], rsum[4] = {0.f, 0.f, 0.f, 0.f};
#pragma unroll
    for (int r = 0; r < 4; ++r) {
      float mn = fmaxf(mrow[r], tmax[r]);
      scl[r] = expf(mrow[r] - mn);   // mrow init -1e30 -> exp underflows to 0
      mrow[r] = mn;
    }
#pragma unroll
    for (int nf = 0; nf < 4; ++nf) {
      int sl = c + nf * 16;
#pragma unroll
      for (int r = 0; r < 4; ++r) {
        float p = expf(sacc[nf][r] - mrow[r]);
        rsum[r] += p;
        *(bf16*)((char*)Ps + swz(((trl + r) * 64 + sl) * 2)) = (bf16)p;
      }
    }
#pragma unroll
    for (int mm = 1; mm < 16; mm <<= 1)
#pragma unroll
      for (int r = 0; r < 4; ++r)
        rsum[r] += __shfl_xor(rsum[r], mm, 64);
#pragma unroll
    for (int r = 0; r < 4; ++r) lrow[r] = lrow[r] * scl[r] + rsum[r];
#pragma unroll
    for (int nf = 0; nf < 4; ++nf)
#pragma unroll
      for (int r = 0; r < 4; ++r) o[nf][r] *= scl[r];
    // PV (P rows are wave-private; compiler orders the LDS write->read)
#pragma unroll
    for (int kk = 0; kk < 2; ++kk) {
      bf16x8 pa = *(const bf16x8*)((char*)Ps + swz((w * 16 + c) * 128 + (kk * 32 + g * 8) * 2));
#pragma unroll
      for (int nf = 0; nf < 4; ++nf) {
        bf16x8 vb = *(const bf16x8*)((char*)Vt + swz((c + nf * 16) * 128 + (kk * 32 + g * 8) * 2));
        o[nf] = __builtin_amdgcn_mfma_f32_16x16x32_bf16(pa, vb, o[nf], 0, 0, 0);
      }
    }
  }
  // epilogue: write attn (pre-Wo) as bf16 [T][B][E]
#pragma unroll
  for (int nf = 0; nf < 4; ++nf)
#pragma unroll
    for (int r = 0; r < 4; ++r) {
      int t = t0 + trl + r;
      int d = c + nf * 16;
      float v = o[nf][r] / lrow[r];
      attn_out[((size_t)t * NBATCH + b) * EMB + h * HD + d] = (bf16)v;
    }
}

extern "C" void kernel_launch(void* const* d_in, const int* in_sizes, int n_in,
                              void* d_out, int out_size, void* d_ws, size_t ws_size,
                              hipStream_t stream) {
  const float* query = (const float*)d_in[0];
  const float* key_ = (const float*)d_in[1];
  const float* value = (const float*)d_in[2];
  const unsigned char* kpm = (const unsigned char*)d_in[3];
  const float* Wq = (const float*)d_in[4];
  const float* bq = (const float*)d_in[5];
  const float* Wk = (const float*)d_in[6];
  const float* bk = (const float*)d_in[7];
  const float* Wv = (const float*)d_in[8];
  const float* bv = (const float*)d_in[9];
  const float* Wo = (const float*)d_in[10];
  const float* bo = (const float*)d_in[11];
  const float* rel_bias = (const float*)d_in[12];
  float* out = (float*)d_out;

  char* ws = (char*)d_ws;
  const size_t SZ = (size_t)SEQ * NBATCH * EMB * sizeof(bf16);  // 6 MB each
  bf16* qhb = (bf16*)(ws);
  bf16* khb = (bf16*)(ws + SZ);
  bf16* vhb = (bf16*)(ws + 2 * SZ);
  bf16* attnb = (bf16*)(ws + 3 * SZ);
  float* bias_tab = (float*)(ws + 4 * SZ);  // 12*4095 f32

  k_bias_table<<<16, 256, 0, stream>>>(rel_bias, bias_tab);
  k_proj_qkv<<<dim3(64, 12), 256, 0, stream>>>(query, Wq, bq, qhb, 0.125f);
  k_proj_qkv<<<dim3(64, 12), 256, 0, stream>>>(key_, Wk, bk, khb, 1.0f);
  k_proj_qkv<<<dim3(64, 12), 256, 0, stream>>>(value, Wv, bv, vhb, 1.0f);
  k_attn<<<dim3(NBATCH * NH, SEQ / 64), 256, 0, stream>>>(qhb, khb, vhb, kpm, bias_tab, attnb);
  k_proj_out<<<dim3(64, 12), 256, 0, stream>>>(attnb, Wo, bo, out);
}

// Round 2
// 202.082 us; speedup vs baseline: 1.4146x; 1.4146x over previous
//
#include <hip/hip_runtime.h>
#include <hip/hip_bf16.h>

typedef __bf16 bf16;
typedef __bf16 bf16x8 __attribute__((ext_vector_type(8)));
typedef float f32x4 __attribute__((ext_vector_type(4)));

#define EMB 768
#define NH 12
#define HD 64
#define SEQ 2048
#define NBATCH 2
#define NREL (2 * SEQ - 1)

// XOR-swizzle for 128B-row-stride LDS tiles (bits 9:7 -> 6:4).
__device__ __forceinline__ int swz(int bo) { return bo ^ ((bo >> 3) & 0x70); }

// ---------------- bias bucket table: bias_tab[h][rel + 2047] ----------------
__global__ void k_bias_table(const float* __restrict__ rel_bias,
                             float* __restrict__ bias_tab) {
  int i = blockIdx.x * 256 + threadIdx.x;
  if (i >= NREL) return;
  int rel = i - (SEQ - 1);            // rel = s - t
  int bkt = (rel > 0) ? 16 : 0;
  int rp = rel < 0 ? -rel : rel;
  if (rp < 8) {
    bkt += rp;
  } else {
    float lf = (logf((float)rp * 0.125f) / 2.7725887222397811f) * 8.0f;
    int large = 8 + (int)lf;
    bkt += (large < 15) ? large : 15;
  }
  for (int h = 0; h < NH; ++h)
    bias_tab[h * NREL + i] = rel_bias[bkt * NH + h];
}

// ---- fused QKV projection: z=0 Q (scaled), z=1 K, z=2 V (transposed out) ---
__global__ __launch_bounds__(256) void k_proj_qkv(
    const float* __restrict__ Aq, const float* __restrict__ Ak,
    const float* __restrict__ Av, const float* __restrict__ Wq,
    const float* __restrict__ Wk, const float* __restrict__ Wv,
    const float* __restrict__ bq, const float* __restrict__ bk,
    const float* __restrict__ bv, bf16* __restrict__ oq,
    bf16* __restrict__ ok, bf16* __restrict__ ov) {
  const int z = blockIdx.z;
  const float* A = z == 0 ? Aq : z == 1 ? Ak : Av;
  const float* W = z == 0 ? Wq : z == 1 ? Wk : Wv;
  const float* bias = z == 0 ? bq : z == 1 ? bk : bv;
  bf16* outh = z == 0 ? oq : z == 1 ? ok : ov;
  const float scale = z == 0 ? 0.125f : 1.0f;

  __shared__ __align__(16) bf16 As[64 * 32];   // [m][k]
  __shared__ __align__(16) bf16 Bs[64 * 32];   // [n][k]
  const int m0 = blockIdx.x * 64, n0 = blockIdx.y * 64;
  const int tid = threadIdx.x;
  const int lane = tid & 63, w = tid >> 6;
  const int c = lane & 15, g = lane >> 4;
  const int mo = (w >> 1) * 32, no = (w & 1) * 32;
  f32x4 acc[2][2] = {};
  for (int k0 = 0; k0 < EMB; k0 += 32) {
    __syncthreads();
    {
      const int row = tid >> 2, kc = (tid & 3) * 8;
      const float* ap = A + (size_t)(m0 + row) * EMB + k0 + kc;
      float4 f0 = *(const float4*)ap;
      float4 f1 = *(const float4*)(ap + 4);
      bf16x8 v;
      v[0] = (bf16)f0.x; v[1] = (bf16)f0.y; v[2] = (bf16)f0.z; v[3] = (bf16)f0.w;
      v[4] = (bf16)f1.x; v[5] = (bf16)f1.y; v[6] = (bf16)f1.z; v[7] = (bf16)f1.w;
      *(bf16x8*)&As[row * 32 + kc] = v;
      const int kr = tid >> 3, nc = (tid & 7) * 8;
      const float* wp = W + (size_t)(k0 + kr) * EMB + n0 + nc;
      float4 w0 = *(const float4*)wp;
      float4 w1 = *(const float4*)(wp + 4);
      float wv[8] = {w0.x, w0.y, w0.z, w0.w, w1.x, w1.y, w1.z, w1.w};
#pragma unroll
      for (int j = 0; j < 8; ++j) Bs[(nc + j) * 32 + kr] = (bf16)wv[j];
    }
    __syncthreads();
#pragma unroll
    for (int mf = 0; mf < 2; ++mf) {
      bf16x8 a = *(const bf16x8*)&As[(mo + mf * 16 + c) * 32 + g * 8];
#pragma unroll
      for (int nf = 0; nf < 2; ++nf) {
        bf16x8 bfr = *(const bf16x8*)&Bs[(no + nf * 16 + c) * 32 + g * 8];
        acc[mf][nf] = __builtin_amdgcn_mfma_f32_16x16x32_bf16(a, bfr, acc[mf][nf], 0, 0, 0);
      }
    }
  }
#pragma unroll
  for (int mf = 0; mf < 2; ++mf)
#pragma unroll
    for (int nf = 0; nf < 2; ++nf)
#pragma unroll
      for (int r = 0; r < 4; ++r) {
        int m = m0 + mo + mf * 16 + g * 4 + r;
        int n = n0 + no + nf * 16 + c;
        float v = (acc[mf][nf][r] + bias[n]) * scale;
        int t = m >> 1, b = m & 1;       // row = t*B + b
        int h = n >> 6, d = n & 63;
        if (z == 2)   // V^T: [B][H][D][S]
          outh[((size_t)(b * NH + h) * HD + d) * SEQ + t] = (bf16)v;
        else          // [B][H][T][D]
          outh[((size_t)(b * NH + h) * SEQ + t) * HD + d] = (bf16)v;
      }
}

// ------------- output projection: bf16 A[4096][768] @ Wo + bo -> f32 --------
__global__ __launch_bounds__(256) void k_proj_out(
    const bf16* __restrict__ A, const float* __restrict__ W,
    const float* __restrict__ bias, float* __restrict__ out) {
  __shared__ __align__(16) bf16 As[64 * 32];
  __shared__ __align__(16) bf16 Bs[64 * 32];
  const int m0 = blockIdx.x * 64, n0 = blockIdx.y * 64;
  const int tid = threadIdx.x;
  const int lane = tid & 63, w = tid >> 6;
  const int c = lane & 15, g = lane >> 4;
  const int mo = (w >> 1) * 32, no = (w & 1) * 32;
  f32x4 acc[2][2] = {};
  for (int k0 = 0; k0 < EMB; k0 += 32) {
    __syncthreads();
    {
      const int row = tid >> 2, kc = (tid & 3) * 8;
      *(bf16x8*)&As[row * 32 + kc] =
          *(const bf16x8*)(A + (size_t)(m0 + row) * EMB + k0 + kc);
      const int kr = tid >> 3, nc = (tid & 7) * 8;
      const float* wp = W + (size_t)(k0 + kr) * EMB + n0 + nc;
      float4 w0 = *(const float4*)wp;
      float4 w1 = *(const float4*)(wp + 4);
      float wv[8] = {w0.x, w0.y, w0.z, w0.w, w1.x, w1.y, w1.z, w1.w};
#pragma unroll
      for (int j = 0; j < 8; ++j) Bs[(nc + j) * 32 + kr] = (bf16)wv[j];
    }
    __syncthreads();
#pragma unroll
    for (int mf = 0; mf < 2; ++mf) {
      bf16x8 a = *(const bf16x8*)&As[(mo + mf * 16 + c) * 32 + g * 8];
#pragma unroll
      for (int nf = 0; nf < 2; ++nf) {
        bf16x8 bfr = *(const bf16x8*)&Bs[(no + nf * 16 + c) * 32 + g * 8];
        acc[mf][nf] = __builtin_amdgcn_mfma_f32_16x16x32_bf16(a, bfr, acc[mf][nf], 0, 0, 0);
      }
    }
  }
#pragma unroll
  for (int mf = 0; mf < 2; ++mf)
#pragma unroll
    for (int nf = 0; nf < 2; ++nf)
#pragma unroll
      for (int r = 0; r < 4; ++r) {
        int m = m0 + mo + mf * 16 + g * 4 + r;
        int n = n0 + no + nf * 16 + c;
        out[(size_t)m * EMB + n] = acc[mf][nf][r] + bias[n];
      }
}

// ----------------------------- flash attention ------------------------------
// Swapped QK^T: sacc = mfma(K_perm, Q) -> S^T fragments; softmax fully
// in-register (lane (c,g) owns row t=w*16+c, 16 s-values); P feeds PV's
// A-operand directly thanks to the K-row permutation pos(s).
__global__ __launch_bounds__(256) void k_attn(
    const bf16* __restrict__ qh, const bf16* __restrict__ kh,
    const bf16* __restrict__ vtg, const unsigned char* __restrict__ mask,
    const float* __restrict__ bias_tab, bf16* __restrict__ attn_out) {
  __shared__ __align__(16) bf16 Ks[64 * 64];   // [pos(s)][d]  swizzled
  __shared__ __align__(16) bf16 Vt[64 * 64];   // [d][s]       swizzled
  __shared__ float bloc[128];
  __shared__ unsigned char mloc[64];
  const int bh = blockIdx.x;
  const int b = bh / NH, h = bh % NH;
  const int t0 = blockIdx.y * 64;
  const int tid = threadIdx.x;
  const int lane = tid & 63, w = tid >> 6;
  const int c = lane & 15, g = lane >> 4;
  const float NEGINF = -__builtin_inff();
  const int tl = w * 16 + c;                   // this lane's t (block-local)

  // Q fragments (B operand), loop-invariant: Q[t0+tl][kk*32 + g*8 ..]
  bf16x8 qf[2];
  {
    const bf16* qp = qh + ((size_t)bh * SEQ + t0 + tl) * HD + g * 8;
    qf[0] = *(const bf16x8*)qp;
    qf[1] = *(const bf16x8*)(qp + 32);
  }
  float m_p = -1e30f, l_p = 0.f;
  f32x4 o[4] = {};
  const float* btab = bias_tab + h * NREL + (SEQ - 1);

  for (int s0 = 0; s0 < SEQ; s0 += 64) {
    __syncthreads();
    {
      const uint4* kg = (const uint4*)(kh + ((size_t)bh * SEQ + s0) * HD);
      for (int i = tid; i < 512; i += 256) {
        int s = i >> 3, c16 = i & 7;
        // pos(s): row permutation so PV A-frag is lane-local
        int pos = (s & 0x23) | ((s & 0x04) << 2) | ((s & 0x18) >> 1);
        *(uint4*)((char*)Ks + swz(pos * 128 + c16 * 16)) = kg[i];
      }
      const bf16* vgb = vtg + (size_t)bh * HD * SEQ + s0;
      for (int i = tid; i < 512; i += 256) {
        int d = i >> 3, c16 = i & 7;
        *(uint4*)((char*)Vt + swz(d * 128 + c16 * 16)) =
            *(const uint4*)(vgb + (size_t)d * SEQ + c16 * 8);
      }
      if (tid < 127) bloc[tid] = btab[(s0 - t0) + tid - 63];
      if (tid < 64) mloc[tid] = mask[b * SEQ + s0 + tid];
    }
    __syncthreads();

    // QK^T (swapped): sacc[nf] holds S[t=t0+tl][s0 + sval(nf,g,r)]
    f32x4 sacc[4] = {};
#pragma unroll
    for (int kk = 0; kk < 2; ++kk) {
#pragma unroll
      for (int nf = 0; nf < 4; ++nf) {
        bf16x8 kf = *(const bf16x8*)((char*)Ks + swz((nf * 16 + c) * 128 + kk * 64 + g * 16));
        sacc[nf] = __builtin_amdgcn_mfma_f32_16x16x32_bf16(kf, qf[kk], sacc[nf], 0, 0, 0);
      }
    }
    // bias + mask + in-lane row-max; sval = 32*(nf>>1) + g*8 + (nf&1)*4 + r
    float p[4][4];
    float tmax = NEGINF;
#pragma unroll
    for (int nf = 0; nf < 4; ++nf) {
      int sb = 32 * (nf >> 1) + g * 8 + (nf & 1) * 4;
#pragma unroll
      for (int r = 0; r < 4; ++r) {
        int sl = sb + r;
        float v = sacc[nf][r] + bloc[sl - tl + 63];
        if (mloc[sl]) v = NEGINF;
        p[nf][r] = v;
        tmax = fmaxf(tmax, v);
      }
    }
    tmax = fmaxf(tmax, __shfl_xor(tmax, 16, 64));
    tmax = fmaxf(tmax, __shfl_xor(tmax, 32, 64));
    float m_new = fmaxf(m_p, tmax);
    float scl_p = __expf(m_p - m_new);
    m_p = m_new;
    float rsum = 0.f;
#pragma unroll
    for (int nf = 0; nf < 4; ++nf)
#pragma unroll
      for (int r = 0; r < 4; ++r) {
        float e = __expf(p[nf][r] - m_new);
        p[nf][r] = e;
        rsum += e;
      }
    rsum += __shfl_xor(rsum, 16, 64);
    rsum += __shfl_xor(rsum, 32, 64);
    l_p = l_p * scl_p + rsum;
    // rescale O (O-layout rows t = w*16 + g*4 + r)
#pragma unroll
    for (int r = 0; r < 4; ++r) {
      float so = __shfl(scl_p, g * 4 + r, 64);
#pragma unroll
      for (int nf2 = 0; nf2 < 4; ++nf2) o[nf2][r] *= so;
    }
    // P -> bf16 A-fragments (pure in-register)
    bf16x8 pa[2];
#pragma unroll
    for (int kk = 0; kk < 2; ++kk)
#pragma unroll
      for (int j = 0; j < 8; ++j)
        pa[kk][j] = (bf16)p[2 * kk + (j >> 2)][j & 3];
    // PV
#pragma unroll
    for (int kk = 0; kk < 2; ++kk) {
#pragma unroll
      for (int nf2 = 0; nf2 < 4; ++nf2) {
        bf16x8 vb = *(const bf16x8*)((char*)Vt + swz((nf2 * 16 + c) * 128 + kk * 64 + g * 16));
        o[nf2] = __builtin_amdgcn_mfma_f32_16x16x32_bf16(pa[kk], vb, o[nf2], 0, 0, 0);
      }
    }
  }
  // epilogue: O rows t = t0 + w*16 + g*4 + r; l lives at lane c'=g*4+r
#pragma unroll
  for (int r = 0; r < 4; ++r) {
    float lo = __shfl(l_p, g * 4 + r, 64);
    float inv = 1.0f / lo;
    int t = t0 + w * 16 + g * 4 + r;
#pragma unroll
    for (int nf2 = 0; nf2 < 4; ++nf2) {
      int d = nf2 * 16 + c;
      attn_out[((size_t)t * NBATCH + b) * EMB + h * HD + d] = (bf16)(o[nf2][r] * inv);
    }
  }
}

extern "C" void kernel_launch(void* const* d_in, const int* in_sizes, int n_in,
                              void* d_out, int out_size, void* d_ws, size_t ws_size,
                              hipStream_t stream) {
  const float* query = (const float*)d_in[0];
  const float* key_ = (const float*)d_in[1];
  const float* value = (const float*)d_in[2];
  const unsigned char* kpm = (const unsigned char*)d_in[3];
  const float* Wq = (const float*)d_in[4];
  const float* bq = (const float*)d_in[5];
  const float* Wk = (const float*)d_in[6];
  const float* bk = (const float*)d_in[7];
  const float* Wv = (const float*)d_in[8];
  const float* bv = (const float*)d_in[9];
  const float* Wo = (const float*)d_in[10];
  const float* bo = (const float*)d_in[11];
  const float* rel_bias = (const float*)d_in[12];
  float* out = (float*)d_out;

  char* ws = (char*)d_ws;
  const size_t SZ = (size_t)SEQ * NBATCH * EMB * sizeof(bf16);  // 6 MB each
  bf16* qhb = (bf16*)(ws);
  bf16* khb = (bf16*)(ws + SZ);
  bf16* vtb = (bf16*)(ws + 2 * SZ);   // V^T: [B][H][D][S]
  bf16* attnb = (bf16*)(ws + 3 * SZ);
  float* bias_tab = (float*)(ws + 4 * SZ);  // 12*4095 f32

  k_bias_table<<<16, 256, 0, stream>>>(rel_bias, bias_tab);
  k_proj_qkv<<<dim3(64, 12, 3), 256, 0, stream>>>(
      query, key_, value, Wq, Wk, Wv, bq, bk, bv, qhb, khb, vtb);
  k_attn<<<dim3(NBATCH * NH, SEQ / 64), 256, 0, stream>>>(qhb, khb, vtb, kpm, bias_tab, attnb);
  k_proj_out<<<dim3(64, 12), 256, 0, stream>>>(attnb, Wo, bo, out);
}

// Round 3
// 167.561 us; speedup vs baseline: 1.7060x; 1.2060x over previous
//
#include <hip/hip_runtime.h>
#include <hip/hip_bf16.h>

typedef __bf16 bf16;
typedef __bf16 bf16x8 __attribute__((ext_vector_type(8)));
typedef float f32x4 __attribute__((ext_vector_type(4)));

#define EMB 768
#define NH 12
#define HD 64
#define SEQ 2048
#define NBATCH 2
#define NREL (2 * SEQ - 1)

// XOR-swizzle for 128B-row-stride LDS tiles (bits 9:7 -> 6:4). Involution.
__device__ __forceinline__ int swz(int bo) { return bo ^ ((bo >> 3) & 0x70); }

// global -> LDS async 16B copy. LDS dest must be wave-uniform; lane i lands
// at dest + i*16. Global src is per-lane.
typedef __attribute__((address_space(3))) unsigned int lds_u32;
typedef __attribute__((address_space(1))) unsigned int glb_u32;
__device__ __forceinline__ void gld16(const void* g, void* l) {
  __builtin_amdgcn_global_load_lds((const glb_u32*)g, (lds_u32*)l, 16, 0, 0);
}

// ---------------- bias bucket table: bias_tab[h][rel + 2047] ----------------
__global__ void k_bias_table(const float* __restrict__ rel_bias,
                             float* __restrict__ bias_tab) {
  int i = blockIdx.x * 256 + threadIdx.x;
  if (i >= NREL) return;
  int rel = i - (SEQ - 1);            // rel = s - t
  int bkt = (rel > 0) ? 16 : 0;
  int rp = rel < 0 ? -rel : rel;
  if (rp < 8) {
    bkt += rp;
  } else {
    float lf = (logf((float)rp * 0.125f) / 2.7725887222397811f) * 8.0f;
    int large = 8 + (int)lf;
    bkt += (large < 15) ? large : 15;
  }
  for (int h = 0; h < NH; ++h)
    bias_tab[h * NREL + i] = rel_bias[bkt * NH + h];
}

// ------- W convert+transpose: W[k][n] f32 -> Wt[n][k] bf16 (z: q,k,v,o) -----
__global__ __launch_bounds__(256) void k_cvt_w(
    const float* __restrict__ Wq, const float* __restrict__ Wk,
    const float* __restrict__ Wv, const float* __restrict__ Wo,
    bf16* __restrict__ Wt3, bf16* __restrict__ Wto) {
  const int z = blockIdx.z;
  const float* W = z == 0 ? Wq : z == 1 ? Wk : z == 2 ? Wv : Wo;
  bf16* O = z < 3 ? Wt3 + (size_t)z * EMB * EMB : Wto;
  int n = blockIdx.y * 64 + (threadIdx.x >> 2);
  int ks = blockIdx.x * 64 + (threadIdx.x & 3) * 16;
  union { bf16 e[16]; uint4 u[2]; } pk;
#pragma unroll
  for (int j = 0; j < 16; ++j)
    pk.e[j] = (bf16)W[(size_t)(ks + j) * EMB + n];
  *(uint4*)(O + (size_t)n * EMB + ks) = pk.u[0];
  *(uint4*)(O + (size_t)n * EMB + ks + 8) = pk.u[1];
}

// ---- QKV projection GEMM: 128x128 tile, BK=64 (m97 structure) --------------
// C[m][n] bf16 = (X[m][:] @ Wt[n][:] + bias[n]) * scale, row-major [4096][768]
__global__ __launch_bounds__(256) void k_proj_qkv(
    const float* __restrict__ Xq, const float* __restrict__ Xk,
    const float* __restrict__ Xv, const bf16* __restrict__ Wt3,
    const float* __restrict__ bq, const float* __restrict__ bk,
    const float* __restrict__ bv, bf16* __restrict__ oq,
    bf16* __restrict__ ok, bf16* __restrict__ ov) {
  __shared__ __align__(16) bf16 As[128 * 64];   // [m][k] linear
  __shared__ __align__(16) bf16 Bs[128 * 64];   // [n][k] linear
  const int z = blockIdx.z;
  const float* X = z == 0 ? Xq : z == 1 ? Xk : Xv;
  const bf16* Wt = Wt3 + (size_t)z * EMB * EMB;
  const float* bias = z == 0 ? bq : z == 1 ? bk : bv;
  bf16* C = z == 0 ? oq : z == 1 ? ok : ov;
  const float scale = z == 0 ? 0.125f : 1.0f;

  const int m0 = blockIdx.x * 128, n0 = blockIdx.y * 128;
  const int tid = threadIdx.x, lane = tid & 63, w = tid >> 6;
  const int c = lane & 15, g = lane >> 4;
  const int mo = (w >> 1) * 64, no = (w & 1) * 64;

  f32x4 acc[4][4] = {};
  for (int k0 = 0; k0 < EMB; k0 += 64) {
    __syncthreads();
    // B-tile via global_load_lds (linear: chunk (w*4+jj) covers 8 rows)
#pragma unroll
    for (int jj = 0; jj < 4; ++jj) {
      int r = w * 32 + jj * 8 + (lane >> 3);
      gld16(Wt + (size_t)(n0 + r) * EMB + k0 + (lane & 7) * 8,
            (char*)Bs + (w * 32 + jj * 8) * 128);
    }
    // A-tile reg-staged (f32 -> bf16), same linear layout
#pragma unroll
    for (int j = 0; j < 4; ++j) {
      int row = (tid >> 3) + j * 32;
      const float* ap = X + (size_t)(m0 + row) * EMB + k0 + (tid & 7) * 8;
      float4 f0 = *(const float4*)ap, f1 = *(const float4*)(ap + 4);
      bf16x8 hh;
      hh[0] = (bf16)f0.x; hh[1] = (bf16)f0.y; hh[2] = (bf16)f0.z; hh[3] = (bf16)f0.w;
      hh[4] = (bf16)f1.x; hh[5] = (bf16)f1.y; hh[6] = (bf16)f1.z; hh[7] = (bf16)f1.w;
      *(bf16x8*)((char*)As + tid * 16 + j * 4096) = hh;
    }
    __syncthreads();
#pragma unroll
    for (int kk = 0; kk < 2; ++kk) {
      bf16x8 av[4], bvf[4];
#pragma unroll
      for (int mf = 0; mf < 4; ++mf)
        av[mf] = *(const bf16x8*)((char*)As + (mo + mf * 16 + c) * 128 + kk * 64 + g * 16);
#pragma unroll
      for (int nf = 0; nf < 4; ++nf)
        bvf[nf] = *(const bf16x8*)((char*)Bs + (no + nf * 16 + c) * 128 + kk * 64 + g * 16);
#pragma unroll
      for (int mf = 0; mf < 4; ++mf)
#pragma unroll
        for (int nf = 0; nf < 4; ++nf)
          acc[mf][nf] = __builtin_amdgcn_mfma_f32_16x16x32_bf16(bvf[nf], av[mf], acc[mf][nf], 0, 0, 0);
    }
  }
  // swapped-operand epilogue: acc[mf][nf][r] = C[mo+mf*16+c][no+nf*16+g*4+r]
#pragma unroll
  for (int nf = 0; nf < 4; ++nf) {
    int n = n0 + no + nf * 16 + g * 4;
    float4 b4 = *(const float4*)&bias[n];
#pragma unroll
    for (int mf = 0; mf < 4; ++mf) {
      int m = m0 + mo + mf * 16 + c;
      union { bf16 e[4]; uint2 u; } pk;
      pk.e[0] = (bf16)((acc[mf][nf][0] + b4.x) * scale);
      pk.e[1] = (bf16)((acc[mf][nf][1] + b4.y) * scale);
      pk.e[2] = (bf16)((acc[mf][nf][2] + b4.z) * scale);
      pk.e[3] = (bf16)((acc[mf][nf][3] + b4.w) * scale);
      *(uint2*)(C + (size_t)m * EMB + n) = pk.u;
    }
  }
}

// ---- output projection: bf16 A[4096][768] @ Wto[n][k] + bo -> f32 ----------
__global__ __launch_bounds__(256) void k_proj_out(
    const bf16* __restrict__ A, const bf16* __restrict__ Wt,
    const float* __restrict__ bias, float* __restrict__ out) {
  __shared__ __align__(16) bf16 As[128 * 64];
  __shared__ __align__(16) bf16 Bs[128 * 64];
  const int m0 = blockIdx.x * 128, n0 = blockIdx.y * 128;
  const int tid = threadIdx.x, lane = tid & 63, w = tid >> 6;
  const int c = lane & 15, g = lane >> 4;
  const int mo = (w >> 1) * 64, no = (w & 1) * 64;
  f32x4 acc[4][4] = {};
  for (int k0 = 0; k0 < EMB; k0 += 64) {
    __syncthreads();
#pragma unroll
    for (int jj = 0; jj < 4; ++jj) {
      int r = w * 32 + jj * 8 + (lane >> 3);
      gld16(A + (size_t)(m0 + r) * EMB + k0 + (lane & 7) * 8,
            (char*)As + (w * 32 + jj * 8) * 128);
      gld16(Wt + (size_t)(n0 + r) * EMB + k0 + (lane & 7) * 8,
            (char*)Bs + (w * 32 + jj * 8) * 128);
    }
    __syncthreads();
#pragma unroll
    for (int kk = 0; kk < 2; ++kk) {
      bf16x8 av[4], bvf[4];
#pragma unroll
      for (int mf = 0; mf < 4; ++mf)
        av[mf] = *(const bf16x8*)((char*)As + (mo + mf * 16 + c) * 128 + kk * 64 + g * 16);
#pragma unroll
      for (int nf = 0; nf < 4; ++nf)
        bvf[nf] = *(const bf16x8*)((char*)Bs + (no + nf * 16 + c) * 128 + kk * 64 + g * 16);
#pragma unroll
      for (int mf = 0; mf < 4; ++mf)
#pragma unroll
        for (int nf = 0; nf < 4; ++nf)
          acc[mf][nf] = __builtin_amdgcn_mfma_f32_16x16x32_bf16(bvf[nf], av[mf], acc[mf][nf], 0, 0, 0);
    }
  }
#pragma unroll
  for (int nf = 0; nf < 4; ++nf) {
    int n = n0 + no + nf * 16 + g * 4;
    float4 b4 = *(const float4*)&bias[n];
#pragma unroll
    for (int mf = 0; mf < 4; ++mf) {
      int m = m0 + mo + mf * 16 + c;
      float4 v;
      v.x = acc[mf][nf][0] + b4.x;
      v.y = acc[mf][nf][1] + b4.y;
      v.z = acc[mf][nf][2] + b4.z;
      v.w = acc[mf][nf][3] + b4.w;
      *(float4*)(out + (size_t)m * EMB + n) = v;
    }
  }
}

// ---- V transpose: vb[4096][768] -> vt[B*H][64][2048] -----------------------
__global__ __launch_bounds__(256) void k_tr_v(const bf16* __restrict__ vb,
                                              bf16* __restrict__ vt) {
  __shared__ __align__(16) bf16 T[64 * 64];  // [s][d] swizzled
  const int bh = blockIdx.x;
  const int b = bh / NH, h = bh % NH;
  const int s0 = blockIdx.y * 64;
  const int tid = threadIdx.x;
#pragma unroll
  for (int ii = 0; ii < 2; ++ii) {
    int i = tid * 2 + ii;
    int s = i >> 3, c16 = i & 7;
    uint4 v = *(const uint4*)(vb + (size_t)((s0 + s) * NBATCH + b) * EMB + h * 64 + c16 * 8);
    *(uint4*)((char*)T + swz(s * 128 + c16 * 16)) = v;
  }
  __syncthreads();
#pragma unroll
  for (int jj = 0; jj < 2; ++jj) {
    int j = tid * 2 + jj;
    int d = j >> 3, sc = (j & 7) * 8;
    union { bf16 e[8]; uint4 u; } pk;
#pragma unroll
    for (int q = 0; q < 8; ++q)
      pk.e[q] = *(const bf16*)((char*)T + swz((sc + q) * 128 + d * 2));
    *(uint4*)(vt + ((size_t)bh * 64 + d) * SEQ + s0 + sc) = pk.u;
  }
}

// ----------------------------- flash attention ------------------------------
// Swapped QK^T + in-register softmax (round-2 verified structure).
// Q,K read from row-major [4096][768]; V from vt [B*H][64][2048].
__global__ __launch_bounds__(256) void k_attn(
    const bf16* __restrict__ qb, const bf16* __restrict__ kb,
    const bf16* __restrict__ vtg, const unsigned char* __restrict__ mask,
    const float* __restrict__ bias_tab, bf16* __restrict__ attn_out) {
  __shared__ __align__(16) bf16 Ks[64 * 64];   // [pos(s)][d]  swizzled
  __shared__ __align__(16) bf16 Vt[64 * 64];   // [d][s]       swizzled
  __shared__ float bloc[128];
  __shared__ unsigned char mloc[64];
  const int bh = blockIdx.x;
  const int b = bh / NH, h = bh % NH;
  const int t0 = blockIdx.y * 64;
  const int tid = threadIdx.x;
  const int lane = tid & 63, w = tid >> 6;
  const int c = lane & 15, g = lane >> 4;
  const float NEGINF = -__builtin_inff();
  const int tl = w * 16 + c;                   // this lane's t (block-local)

  bf16x8 qf[2];
  {
    const bf16* qp = qb + (size_t)((t0 + tl) * NBATCH + b) * EMB + h * 64 + g * 8;
    qf[0] = *(const bf16x8*)qp;
    qf[1] = *(const bf16x8*)(qp + 32);
  }
  float m_p = -1e30f, l_p = 0.f;
  f32x4 o[4] = {};
  const float* btab = bias_tab + h * NREL + (SEQ - 1);

  for (int s0 = 0; s0 < SEQ; s0 += 64) {
    __syncthreads();
    {
      for (int i = tid; i < 512; i += 256) {
        int s = i >> 3, c16 = i & 7;
        uint4 kv = *(const uint4*)(kb + (size_t)((s0 + s) * NBATCH + b) * EMB + h * 64 + c16 * 8);
        int pos = (s & 0x23) | ((s & 0x04) << 2) | ((s & 0x18) >> 1);
        *(uint4*)((char*)Ks + swz(pos * 128 + c16 * 16)) = kv;
      }
      const bf16* vgb = vtg + (size_t)bh * HD * SEQ + s0;
      for (int i = tid; i < 512; i += 256) {
        int d = i >> 3, c16 = i & 7;
        *(uint4*)((char*)Vt + swz(d * 128 + c16 * 16)) =
            *(const uint4*)(vgb + (size_t)d * SEQ + c16 * 8);
      }
      if (tid < 127) bloc[tid] = btab[(s0 - t0) + tid - 63];
      if (tid < 64) mloc[tid] = mask[b * SEQ + s0 + tid];
    }
    __syncthreads();

    f32x4 sacc[4] = {};
#pragma unroll
    for (int kk = 0; kk < 2; ++kk) {
#pragma unroll
      for (int nf = 0; nf < 4; ++nf) {
        bf16x8 kf = *(const bf16x8*)((char*)Ks + swz((nf * 16 + c) * 128 + kk * 64 + g * 16));
        sacc[nf] = __builtin_amdgcn_mfma_f32_16x16x32_bf16(kf, qf[kk], sacc[nf], 0, 0, 0);
      }
    }
    float p[4][4];
    float tmax = NEGINF;
#pragma unroll
    for (int nf = 0; nf < 4; ++nf) {
      int sb = 32 * (nf >> 1) + g * 8 + (nf & 1) * 4;
#pragma unroll
      for (int r = 0; r < 4; ++r) {
        int sl = sb + r;
        float v = sacc[nf][r] + bloc[sl - tl + 63];
        if (mloc[sl]) v = NEGINF;
        p[nf][r] = v;
        tmax = fmaxf(tmax, v);
      }
    }
    tmax = fmaxf(tmax, __shfl_xor(tmax, 16, 64));
    tmax = fmaxf(tmax, __shfl_xor(tmax, 32, 64));
    float m_new = fmaxf(m_p, tmax);
    float scl_p = __expf(m_p - m_new);
    m_p = m_new;
    float rsum = 0.f;
#pragma unroll
    for (int nf = 0; nf < 4; ++nf)
#pragma unroll
      for (int r = 0; r < 4; ++r) {
        float e = __expf(p[nf][r] - m_new);
        p[nf][r] = e;
        rsum += e;
      }
    rsum += __shfl_xor(rsum, 16, 64);
    rsum += __shfl_xor(rsum, 32, 64);
    l_p = l_p * scl_p + rsum;
#pragma unroll
    for (int r = 0; r < 4; ++r) {
      float so = __shfl(scl_p, g * 4 + r, 64);
#pragma unroll
      for (int nf2 = 0; nf2 < 4; ++nf2) o[nf2][r] *= so;
    }
    bf16x8 pa[2];
#pragma unroll
    for (int kk = 0; kk < 2; ++kk)
#pragma unroll
      for (int j = 0; j < 8; ++j)
        pa[kk][j] = (bf16)p[2 * kk + (j >> 2)][j & 3];
#pragma unroll
    for (int kk = 0; kk < 2; ++kk) {
#pragma unroll
      for (int nf2 = 0; nf2 < 4; ++nf2) {
        bf16x8 vbf = *(const bf16x8*)((char*)Vt + swz((nf2 * 16 + c) * 128 + kk * 64 + g * 16));
        o[nf2] = __builtin_amdgcn_mfma_f32_16x16x32_bf16(pa[kk], vbf, o[nf2], 0, 0, 0);
      }
    }
  }
#pragma unroll
  for (int r = 0; r < 4; ++r) {
    float lo = __shfl(l_p, g * 4 + r, 64);
    float inv = 1.0f / lo;
    int t = t0 + w * 16 + g * 4 + r;
#pragma unroll
    for (int nf2 = 0; nf2 < 4; ++nf2) {
      int d = nf2 * 16 + c;
      attn_out[((size_t)t * NBATCH + b) * EMB + h * HD + d] = (bf16)(o[nf2][r] * inv);
    }
  }
}

extern "C" void kernel_launch(void* const* d_in, const int* in_sizes, int n_in,
                              void* d_out, int out_size, void* d_ws, size_t ws_size,
                              hipStream_t stream) {
  const float* query = (const float*)d_in[0];
  const float* key_ = (const float*)d_in[1];
  const float* value = (const float*)d_in[2];
  const unsigned char* kpm = (const unsigned char*)d_in[3];
  const float* Wq = (const float*)d_in[4];
  const float* bq = (const float*)d_in[5];
  const float* Wk = (const float*)d_in[6];
  const float* bk = (const float*)d_in[7];
  const float* Wv = (const float*)d_in[8];
  const float* bv = (const float*)d_in[9];
  const float* Wo = (const float*)d_in[10];
  const float* bo = (const float*)d_in[11];
  const float* rel_bias = (const float*)d_in[12];
  float* out = (float*)d_out;

  char* ws = (char*)d_ws;
  const size_t SZb = (size_t)SEQ * NBATCH * EMB * sizeof(bf16);  // 6.29 MB
  const size_t WSZ = (size_t)EMB * EMB * sizeof(bf16);           // 1.18 MB
  bf16* qbb = (bf16*)(ws);
  bf16* kbb = (bf16*)(ws + SZb);
  bf16* vbb = (bf16*)(ws + 2 * SZb);
  bf16* vtb = (bf16*)(ws + 3 * SZb);
  bf16* attnb = vbb;                       // vb dead after k_tr_v
  bf16* Wt3 = (bf16*)(ws + 4 * SZb);
  bf16* Wto = (bf16*)(ws + 4 * SZb + 3 * WSZ);
  float* bias_tab = (float*)(ws + 4 * SZb + 4 * WSZ);

  k_bias_table<<<16, 256, 0, stream>>>(rel_bias, bias_tab);
  k_cvt_w<<<dim3(12, 12, 4), 256, 0, stream>>>(Wq, Wk, Wv, Wo, Wt3, Wto);
  k_proj_qkv<<<dim3(32, 6, 3), 256, 0, stream>>>(
      query, key_, value, Wt3, bq, bk, bv, qbb, kbb, vbb);
  k_tr_v<<<dim3(NBATCH * NH, SEQ / 64), 256, 0, stream>>>(vbb, vtb);
  k_attn<<<dim3(NBATCH * NH, SEQ / 64), 256, 0, stream>>>(qbb, kbb, vtb, kpm, bias_tab, attnb);
  k_proj_out<<<dim3(32, 6), 256, 0, stream>>>(attnb, Wto, bo, out);
}